// Round 12
// baseline (279.331 us; speedup 1.0000x reference)
//
#include <hip/hip_runtime.h>
#include <hip/hip_bf16.h>

#define N_NODES 50000
#define N_EDGES 800000
#define E_TOT   850000   // edges + self loops
#define IN_DIM  128
#define C1      256      // HEADS*HID
#define HEADS   4
#define HID     64
#define OUT_DIM 32
#define NEG_SLOPE 0.2f
#define SCAN_NBLK 196    // ceil(50000/256)
#define G1_BLOCKS 3125   // 50000/16
#define EDGES_PER_G1 272 // 850000/3125

typedef __attribute__((ext_vector_type(8))) short bf16x8;
typedef __attribute__((ext_vector_type(8))) unsigned short u16x8;
typedef __attribute__((ext_vector_type(4))) float f32x4;

__device__ __forceinline__ void edge_sd(const int* __restrict__ ei, int e, int& s, int& d) {
    if (e < N_EDGES) { s = ei[e]; d = ei[N_EDGES + e]; }
    else             { s = d = e - N_EDGES; }
}

__device__ __forceinline__ unsigned short f2bf(float f) {
    unsigned u = __float_as_uint(f);
    u += 0x7fffu + ((u >> 16) & 1u);   // RNE
    return (unsigned short)(u >> 16);
}
__device__ __forceinline__ float bf2f(unsigned short u) {
    return __uint_as_float(((unsigned)u) << 16);
}
__device__ __forceinline__ float4 bf4_to_f4(ushort4 v) {
    return make_float4(bf2f(v.x), bf2f(v.y), bf2f(v.z), bf2f(v.w));
}
__device__ __forceinline__ float lrelu_exp(float l) {
    return __expf(fmaxf(l, NEG_SLOPE * l));   // slope<1 => lrelu == max(l, 0.2l)
}

// ================================================================ setup: zero deg+counter, pack W1/W2 (bf16 B-fragment order)
__global__ __launch_bounds__(256) void setup_kernel(const float* __restrict__ W1,
                                                    const float* __restrict__ W2,
                                                    unsigned short* __restrict__ Bp1,
                                                    unsigned short* __restrict__ Bp2,
                                                    int* __restrict__ deg) {
    int tid = blockIdx.x * 256 + threadIdx.x;
    if (tid < N_NODES + 1) deg[tid] = 0;   // deg[50000] doubles as the scan arrival counter
    if (tid < IN_DIM * C1) {
        int j = tid & 7, q = (tid >> 3) & 3, n = (tid >> 5) & 255, K0 = tid >> 13;
        int k = K0 * 32 + q * 8 + j;
        Bp1[tid] = f2bf(W1[k * C1 + n]);
        if (tid < C1 * OUT_DIM) {
            int j2 = tid & 7, q2 = (tid >> 3) & 3, n2 = (tid >> 5) & 31, K02 = tid >> 10;
            int k2 = K02 * 32 + q2 * 8 + j2;
            Bp2[tid] = f2bf(W2[k2 * OUT_DIM + n2]);
        }
    }
}

// ================================================================ GEMM1 (MFMA bf16) + fused alpha1 + fused edge-degree count
__global__ __launch_bounds__(256) void gemm1_kernel(const float* __restrict__ x,
                                                    const unsigned short* __restrict__ Bp,
                                                    const float* __restrict__ a_src1,
                                                    const float* __restrict__ a_dst1,
                                                    const int* __restrict__ ei,
                                                    unsigned short* __restrict__ h1b,
                                                    float* __restrict__ as1,
                                                    float* __restrict__ ad1,
                                                    int* __restrict__ deg,
                                                    int* __restrict__ pos) {
    __shared__ unsigned short xs[16][136];  // +8 pad -> 2-way LDS aliasing (free)
    const int t = threadIdx.x;
    const int row0 = blockIdx.x * 16;
    {
        int r = t >> 4, k0 = (t & 15) * 8;
        const float* xp = &x[(size_t)(row0 + r) * IN_DIM + k0];
        float4 v0 = *(const float4*)xp;
        float4 v1 = *(const float4*)(xp + 4);
        ushort4 o0, o1;
        o0.x = f2bf(v0.x); o0.y = f2bf(v0.y); o0.z = f2bf(v0.z); o0.w = f2bf(v0.w);
        o1.x = f2bf(v1.x); o1.y = f2bf(v1.y); o1.z = f2bf(v1.z); o1.w = f2bf(v1.w);
        *(ushort4*)&xs[r][k0] = o0;
        *(ushort4*)&xs[r][k0 + 4] = o1;
    }
    __syncthreads();
    const int wave = t >> 6;         // head index
    const int lane = t & 63;
    const int nl = lane & 15, q = lane >> 4;
    f32x4 acc[4];
    f32x4 z = {0.f, 0.f, 0.f, 0.f};
    acc[0] = z; acc[1] = z; acc[2] = z; acc[3] = z;
#pragma unroll
    for (int K0 = 0; K0 < 4; ++K0) {
        bf16x8 af = *(const bf16x8*)&xs[nl][K0 * 32 + q * 8];
#pragma unroll
        for (int sub = 0; sub < 4; ++sub) {
            int n = wave * 64 + sub * 16 + nl;
            bf16x8 bfv = *(const bf16x8*)&Bp[((size_t)(K0 * 256 + n) * 4 + q) * 8];
            acc[sub] = __builtin_amdgcn_mfma_f32_16x16x32_bf16(af, bfv, acc[sub], 0, 0, 0);
        }
    }
    float asv[4], adv[4];
#pragma unroll
    for (int sub = 0; sub < 4; ++sub) {
        asv[sub] = a_src1[wave * 64 + sub * 16 + nl];
        adv[sub] = a_dst1[wave * 64 + sub * 16 + nl];
    }
#pragma unroll
    for (int r = 0; r < 4; ++r) {
        int gr = row0 + q * 4 + r;   // C/D: row = quad*4 + reg, col = lane&15
        float ps = 0.f, pd = 0.f;
#pragma unroll
        for (int sub = 0; sub < 4; ++sub) {
            float v = acc[sub][r];
            h1b[(size_t)gr * C1 + wave * 64 + sub * 16 + nl] = f2bf(v);
            ps += v * asv[sub];
            pd += v * adv[sub];
        }
#pragma unroll
        for (int m = 8; m >= 1; m >>= 1) {
            ps += __shfl_xor(ps, m, 16);
            pd += __shfl_xor(pd, m, 16);
        }
        if (nl == 0) {
            as1[gr * 4 + wave] = ps;
            ad1[gr * 4 + wave] = pd;
        }
    }
    // fused degree count: this block's 272-edge slice
    int base = blockIdx.x * EDGES_PER_G1;
    for (int e = base + t; e < base + EDGES_PER_G1; e += 256) {
        int s, d; edge_sd(ei, e, s, d);
        pos[e] = atomicAdd(&deg[d], 1);
    }
}

// ================================================================ scan: block-local scan + arrival-order chunk base
__global__ __launch_bounds__(256) void scan_kernel(const int* __restrict__ deg,
                                                   int* __restrict__ counter,  // = &deg[50000], zeroed
                                                   int* __restrict__ row_start) {
    __shared__ int sm[256];
    __shared__ int base;
    int t = threadIdx.x, idx = blockIdx.x * 256 + t;
    int v = (idx < N_NODES) ? deg[idx] : 0;
    sm[t] = v; __syncthreads();
#pragma unroll
    for (int off = 1; off < 256; off <<= 1) {
        int u = (t >= off) ? sm[t - off] : 0;
        __syncthreads();
        sm[t] += u;
        __syncthreads();
    }
    if (t == 255) base = atomicAdd(counter, sm[255]);
    __syncthreads();
    if (idx < N_NODES) row_start[idx] = base + sm[t] - v;
}

// ================================================================ scatter: csr_src only (4 B/edge)
__global__ __launch_bounds__(256) void scatter_kernel(const int* __restrict__ ei,
                                                      const int* __restrict__ row_start,
                                                      const int* __restrict__ pos,
                                                      int* __restrict__ csr_src) {
    int e = blockIdx.x * 256 + threadIdx.x;
    if (e >= E_TOT) return;
    int s, d; edge_sd(ei, e, s, d);
    csr_src[row_start[d] + pos[e]] = s;
}

// ================================================================ agg1: head-split, XCD-aware swizzle
// 1 wave = 1 (dst, head): 4 edge slots x 16 lanes x ushort4 (64 feats of that head).
// head = (blockIdx%8)>>1 -> if block->XCD dispatch is round-robin, each XCD touches
// only one head's 6.4 MB slice of h1b (128B-aligned sub-rows -> clean line split).
__global__ __launch_bounds__(256) void agg1_kernel(const int* __restrict__ csr_src,
                                                   const int* __restrict__ row_start,
                                                   const int* __restrict__ deg,
                                                   const unsigned short* __restrict__ h1b,
                                                   const float* __restrict__ as1,
                                                   const float* __restrict__ ad1,
                                                   const float* __restrict__ b1,
                                                   unsigned short* __restrict__ hpb) {
    int b = blockIdx.x;
    int h = (b & 7) >> 1;                       // head: 2 of 8 XCD slots each
    int idx = (b >> 3) * 2 + (b & 1);           // within-head chunk [0, 12500)
    int wave = threadIdx.x >> 6;
    int n = idx * 4 + wave;                     // dst node (12500*4 = 50000, exact)
    int lane = threadIdx.x & 63;
    int g = lane >> 4;                          // edge slot 0..3
    int c = lane & 15;                          // feat chunk: head feats [c*4, c*4+4)
    int beg = __builtin_amdgcn_readfirstlane(row_start[n]);
    int end = beg + __builtin_amdgcn_readfirstlane(deg[n]);
    float ad = ad1[n * 4 + h];
    const size_t hoff = (size_t)h * HID;
    float4 acc = make_float4(0.f, 0.f, 0.f, 0.f);
    float sumw = 0.f;
    int i = beg;
    for (; i + 16 <= end; i += 16) {            // unmasked: 16 edges per iter (4/slot)
        int s[4];
#pragma unroll
        for (int u = 0; u < 4; ++u) s[u] = csr_src[i + u * 4 + g];
        float a[4];
#pragma unroll
        for (int u = 0; u < 4; ++u) a[u] = as1[s[u] * 4 + h];
        ushort4 rv[4];
#pragma unroll
        for (int u = 0; u < 4; ++u)
            rv[u] = *(const ushort4*)&h1b[(size_t)s[u] * C1 + hoff + c * 4];
#pragma unroll
        for (int u = 0; u < 4; ++u) {
            float w = lrelu_exp(a[u] + ad);
            sumw += w;
            float4 f = bf4_to_f4(rv[u]);
            acc.x += w * f.x; acc.y += w * f.y;
            acc.z += w * f.z; acc.w += w * f.w;
        }
    }
    if (i < end) {                               // masked tail: up to 16 edges
        int s[4]; float va[4];
#pragma unroll
        for (int u = 0; u < 4; ++u) {
            int e = i + u * 4 + g;
            bool v = e < end;
            va[u] = v ? 1.f : 0.f;
            s[u] = csr_src[v ? e : beg];         // safe slot (deg >= 1 via self-loop)
        }
        float a[4];
#pragma unroll
        for (int u = 0; u < 4; ++u) a[u] = as1[s[u] * 4 + h];
        ushort4 rv[4];
#pragma unroll
        for (int u = 0; u < 4; ++u)
            rv[u] = *(const ushort4*)&h1b[(size_t)s[u] * C1 + hoff + c * 4];
#pragma unroll
        for (int u = 0; u < 4; ++u) {
            float w = va[u] * lrelu_exp(a[u] + ad);
            sumw += w;
            float4 f = bf4_to_f4(rv[u]);
            acc.x += w * f.x; acc.y += w * f.y;
            acc.z += w * f.z; acc.w += w * f.w;
        }
    }
    // reduce across the 4 edge slots (xor 16, 32)
#pragma unroll
    for (int m = 16; m <= 32; m <<= 1) {
        sumw  += __shfl_xor(sumw, m, 64);
        acc.x += __shfl_xor(acc.x, m, 64);
        acc.y += __shfl_xor(acc.y, m, 64);
        acc.z += __shfl_xor(acc.z, m, 64);
        acc.w += __shfl_xor(acc.w, m, 64);
    }
    if (g == 0) {
        float inv = 1.f / (sumw + 1e-16f);
        const float4 bv = *(const float4*)&b1[hoff + c * 4];
        float v0 = acc.x * inv + bv.x;
        float v1 = acc.y * inv + bv.y;
        float v2 = acc.z * inv + bv.z;
        float v3 = acc.w * inv + bv.w;
        v0 = v0 > 0.f ? v0 : __expf(v0) - 1.f;
        v1 = v1 > 0.f ? v1 : __expf(v1) - 1.f;
        v2 = v2 > 0.f ? v2 : __expf(v2) - 1.f;
        v3 = v3 > 0.f ? v3 : __expf(v3) - 1.f;
        ushort4 o;
        o.x = f2bf(v0); o.y = f2bf(v1); o.z = f2bf(v2); o.w = f2bf(v3);
        *(ushort4*)&hpb[(size_t)n * C1 + hoff + c * 4] = o;
    }
}

// ================================================================ GEMM2 (MFMA bf16) + fused alpha2; h2 stored bf16
__global__ __launch_bounds__(256) void gemm2_kernel(const unsigned short* __restrict__ hpb,
                                                    const unsigned short* __restrict__ Bp2,
                                                    const float* __restrict__ a_src2,
                                                    const float* __restrict__ a_dst2,
                                                    unsigned short* __restrict__ h2b,
                                                    float* __restrict__ as2,
                                                    float* __restrict__ ad2) {
    __shared__ unsigned short xs[64][264];  // stride 264 shorts -> 2-way bank aliasing (free)
    const int t = threadIdx.x;
    const int row0 = blockIdx.x * 64;
    for (int idx = t; idx < 2048; idx += 256) {  // 64 rows x 32 chunks of 8
        int r = idx >> 5, ch = (idx & 31) * 8;
        int gr = row0 + r;
        u16x8 v = {0, 0, 0, 0, 0, 0, 0, 0};
        if (gr < N_NODES) v = *(const u16x8*)&hpb[(size_t)gr * C1 + ch];
        *(u16x8*)&xs[r][ch] = v;
    }
    __syncthreads();
    const int wave = t >> 6, lane = t & 63;
    const int nl = lane & 15, q = lane >> 4;
    f32x4 acc0 = {0.f, 0.f, 0.f, 0.f}, acc1 = {0.f, 0.f, 0.f, 0.f};
#pragma unroll
    for (int K0 = 0; K0 < 8; ++K0) {
        bf16x8 af = *(const bf16x8*)&xs[wave * 16 + nl][K0 * 32 + q * 8];
        bf16x8 b0 = *(const bf16x8*)&Bp2[((size_t)(K0 * 32 + nl) * 4 + q) * 8];
        bf16x8 b1v = *(const bf16x8*)&Bp2[((size_t)(K0 * 32 + 16 + nl) * 4 + q) * 8];
        acc0 = __builtin_amdgcn_mfma_f32_16x16x32_bf16(af, b0, acc0, 0, 0, 0);
        acc1 = __builtin_amdgcn_mfma_f32_16x16x32_bf16(af, b1v, acc1, 0, 0, 0);
    }
    float a_s0 = a_src2[nl], a_s1 = a_src2[16 + nl];
    float a_d0 = a_dst2[nl], a_d1 = a_dst2[16 + nl];
#pragma unroll
    for (int r = 0; r < 4; ++r) {
        int gr = row0 + wave * 16 + q * 4 + r;
        if (gr < N_NODES) {
            h2b[(size_t)gr * OUT_DIM + nl] = f2bf(acc0[r]);
            h2b[(size_t)gr * OUT_DIM + 16 + nl] = f2bf(acc1[r]);
            float ps = acc0[r] * a_s0 + acc1[r] * a_s1;
            float pd = acc0[r] * a_d0 + acc1[r] * a_d1;
#pragma unroll
            for (int m = 8; m >= 1; m >>= 1) {
                ps += __shfl_xor(ps, m, 16);
                pd += __shfl_xor(pd, m, 16);
            }
            if (nl == 0) { as2[gr] = ps; ad2[gr] = pd; }
        }
    }
}

// ================================================================ agg2: 1 wave/dst, 2x8 edges x 8 lanes x ushort4 (bf16 h2)
__global__ __launch_bounds__(256) void agg2_kernel(const int* __restrict__ csr_src,
                                                   const int* __restrict__ row_start,
                                                   const int* __restrict__ deg,
                                                   const unsigned short* __restrict__ h2b,
                                                   const float* __restrict__ as2,
                                                   const float* __restrict__ ad2,
                                                   const float* __restrict__ b2,
                                                   float* __restrict__ out) {
    int n = (blockIdx.x * 256 + threadIdx.x) >> 6;
    if (n >= N_NODES) return;
    int lane = threadIdx.x & 63;
    int g  = lane >> 3;          // edge slot 0..7
    int c4 = lane & 7;           // ushort4 chunk: cols [c4*4, c4*4+4)
    int beg = __builtin_amdgcn_readfirstlane(row_start[n]);
    int end = beg + __builtin_amdgcn_readfirstlane(deg[n]);
    float ad = ad2[n];
    float4 acc = make_float4(0.f, 0.f, 0.f, 0.f);
    float sumw = 0.f;
    for (int i = beg; i < end; i += 16) {        // two 8-edge batches in flight
#pragma unroll
        for (int b = 0; b < 2; ++b) {
            int idx = i + b * 8 + g;
            bool valid = idx < end;
            int ic = valid ? idx : beg;
            int s = csr_src[ic];
            float w = valid ? lrelu_exp(as2[s] + ad) : 0.f;
            sumw += w;
            float4 hv = bf4_to_f4(*(const ushort4*)&h2b[(size_t)s * OUT_DIM + c4 * 4]);
            acc.x += w * hv.x; acc.y += w * hv.y; acc.z += w * hv.z; acc.w += w * hv.w;
        }
    }
#pragma unroll
    for (int m = 8; m <= 32; m <<= 1) {
        sumw  += __shfl_xor(sumw, m, 64);
        acc.x += __shfl_xor(acc.x, m, 64);
        acc.y += __shfl_xor(acc.y, m, 64);
        acc.z += __shfl_xor(acc.z, m, 64);
        acc.w += __shfl_xor(acc.w, m, 64);
    }
    if (g == 0) {
        float inv = 1.f / (sumw + 1e-16f);
        const float4 bv = *(const float4*)&b2[c4 * 4];
        *(float4*)&out[(size_t)n * OUT_DIM + c4 * 4] =
            make_float4(acc.x * inv + bv.x, acc.y * inv + bv.y,
                        acc.z * inv + bv.z, acc.w * inv + bv.w);
    }
}

extern "C" void kernel_launch(void* const* d_in, const int* in_sizes, int n_in,
                              void* d_out, int out_size, void* d_ws, size_t ws_size,
                              hipStream_t stream) {
    const float* x      = (const float*)d_in[0];
    const int*   ei     = (const int*)d_in[1];
    const float* W1     = (const float*)d_in[2];
    const float* a_src1 = (const float*)d_in[3];
    const float* a_dst1 = (const float*)d_in[4];
    const float* b1     = (const float*)d_in[5];
    const float* W2     = (const float*)d_in[6];
    const float* a_src2 = (const float*)d_in[7];
    const float* a_dst2 = (const float*)d_in[8];
    const float* b2     = (const float*)d_in[9];
    float* out = (float*)d_out;

    // workspace layout
    unsigned short* h1b = (unsigned short*)d_ws;        // 12.8M bf16
    unsigned short* hpb = h1b + 12800000;               // 12.8M bf16
    unsigned short* h2b = hpb + 12800000;               // 1.6M bf16
    unsigned short* Bp1 = h2b + 1600000;                // 32768 bf16
    unsigned short* Bp2 = Bp1 + 32768;                  // 8192 bf16
    float* as1    = (float*)(Bp2 + 8192);               // 200k
    float* ad1    = as1 + 200000;                       // 200k
    float* as2    = ad1 + 200000;                       // 50k
    float* ad2    = as2 + 50000;                        // 50k
    int* csr_src  = (int*)(ad2 + 50000);                // 850k
    int* row_start= csr_src + E_TOT;                    // 50000
    int* deg      = row_start + N_NODES;                // 50001 (last = scan arrival counter)
    int* pos      = deg + N_NODES + 1;                  // 850k

    setup_kernel<<<SCAN_NBLK, 256, 0, stream>>>(W1, W2, Bp1, Bp2, deg);
    gemm1_kernel<<<G1_BLOCKS, 256, 0, stream>>>(x, Bp1, a_src1, a_dst1, ei,
                                                h1b, as1, ad1, deg, pos);
    scan_kernel<<<SCAN_NBLK, 256, 0, stream>>>(deg, deg + N_NODES, row_start);
    scatter_kernel<<<(E_TOT + 255) / 256, 256, 0, stream>>>(ei, row_start, pos, csr_src);
    agg1_kernel<<<N_NODES, 256, 0, stream>>>(csr_src, row_start, deg,
                                             h1b, as1, ad1, b1, hpb);
    gemm2_kernel<<<(N_NODES + 63) / 64, 256, 0, stream>>>(hpb, Bp2, a_src2, a_dst2, h2b, as2, ad2);
    agg2_kernel<<<(N_NODES * 64 + 255) / 256, 256, 0, stream>>>(csr_src, row_start, deg,
                                                                h2b, as2, ad2, b2, out);
}

// Round 13
// 250.126 us; speedup vs baseline: 1.1168x; 1.1168x over previous
//
#include <hip/hip_runtime.h>
#include <hip/hip_bf16.h>

#define N_NODES 50000
#define N_EDGES 800000
#define E_TOT   850000   // edges + self loops
#define IN_DIM  128
#define C1      256      // HEADS*HID
#define HEADS   4
#define HID     64
#define OUT_DIM 32
#define NEG_SLOPE 0.2f
#define SCAN_NBLK 196    // ceil(50000/256)
#define G1_BLOCKS 3125   // 50000/16
#define EDGES_PER_G1 272 // 850000/3125

typedef __attribute__((ext_vector_type(8))) short bf16x8;
typedef __attribute__((ext_vector_type(8))) unsigned short u16x8;
typedef __attribute__((ext_vector_type(4))) float f32x4;

__device__ __forceinline__ void edge_sd(const int* __restrict__ ei, int e, int& s, int& d) {
    if (e < N_EDGES) { s = ei[e]; d = ei[N_EDGES + e]; }
    else             { s = d = e - N_EDGES; }
}

__device__ __forceinline__ unsigned short f2bf(float f) {
    unsigned u = __float_as_uint(f);
    u += 0x7fffu + ((u >> 16) & 1u);   // RNE
    return (unsigned short)(u >> 16);
}
__device__ __forceinline__ float bf2f(unsigned short u) {
    return __uint_as_float(((unsigned)u) << 16);
}
__device__ __forceinline__ float4 bf4_to_f4(ushort4 v) {
    return make_float4(bf2f(v.x), bf2f(v.y), bf2f(v.z), bf2f(v.w));
}
__device__ __forceinline__ float lrelu_exp(float l) {
    return __expf(fmaxf(l, NEG_SLOPE * l));   // slope<1 => lrelu == max(l, 0.2l)
}

// ================================================================ setup: zero deg+counter, pack W1/W2 (bf16 B-fragment order)
__global__ __launch_bounds__(256) void setup_kernel(const float* __restrict__ W1,
                                                    const float* __restrict__ W2,
                                                    unsigned short* __restrict__ Bp1,
                                                    unsigned short* __restrict__ Bp2,
                                                    int* __restrict__ deg) {
    int tid = blockIdx.x * 256 + threadIdx.x;
    if (tid < N_NODES + 1) deg[tid] = 0;   // deg[50000] doubles as the scan arrival counter
    if (tid < IN_DIM * C1) {
        int j = tid & 7, q = (tid >> 3) & 3, n = (tid >> 5) & 255, K0 = tid >> 13;
        int k = K0 * 32 + q * 8 + j;
        Bp1[tid] = f2bf(W1[k * C1 + n]);
        if (tid < C1 * OUT_DIM) {
            int j2 = tid & 7, q2 = (tid >> 3) & 3, n2 = (tid >> 5) & 31, K02 = tid >> 10;
            int k2 = K02 * 32 + q2 * 8 + j2;
            Bp2[tid] = f2bf(W2[k2 * OUT_DIM + n2]);
        }
    }
}

// ================================================================ GEMM1 (MFMA bf16) + fused alpha1 + fused edge-degree count
__global__ __launch_bounds__(256) void gemm1_kernel(const float* __restrict__ x,
                                                    const unsigned short* __restrict__ Bp,
                                                    const float* __restrict__ a_src1,
                                                    const float* __restrict__ a_dst1,
                                                    const int* __restrict__ ei,
                                                    unsigned short* __restrict__ h1b,
                                                    float* __restrict__ as1,
                                                    float* __restrict__ ad1,
                                                    int* __restrict__ deg,
                                                    int* __restrict__ pos) {
    __shared__ unsigned short xs[16][136];  // +8 pad -> 2-way LDS aliasing (free)
    const int t = threadIdx.x;
    const int row0 = blockIdx.x * 16;
    {
        int r = t >> 4, k0 = (t & 15) * 8;
        const float* xp = &x[(size_t)(row0 + r) * IN_DIM + k0];
        float4 v0 = *(const float4*)xp;
        float4 v1 = *(const float4*)(xp + 4);
        ushort4 o0, o1;
        o0.x = f2bf(v0.x); o0.y = f2bf(v0.y); o0.z = f2bf(v0.z); o0.w = f2bf(v0.w);
        o1.x = f2bf(v1.x); o1.y = f2bf(v1.y); o1.z = f2bf(v1.z); o1.w = f2bf(v1.w);
        *(ushort4*)&xs[r][k0] = o0;
        *(ushort4*)&xs[r][k0 + 4] = o1;
    }
    __syncthreads();
    const int wave = t >> 6;         // head index
    const int lane = t & 63;
    const int nl = lane & 15, q = lane >> 4;
    f32x4 acc[4];
    f32x4 z = {0.f, 0.f, 0.f, 0.f};
    acc[0] = z; acc[1] = z; acc[2] = z; acc[3] = z;
#pragma unroll
    for (int K0 = 0; K0 < 4; ++K0) {
        bf16x8 af = *(const bf16x8*)&xs[nl][K0 * 32 + q * 8];
#pragma unroll
        for (int sub = 0; sub < 4; ++sub) {
            int n = wave * 64 + sub * 16 + nl;
            bf16x8 bfv = *(const bf16x8*)&Bp[((size_t)(K0 * 256 + n) * 4 + q) * 8];
            acc[sub] = __builtin_amdgcn_mfma_f32_16x16x32_bf16(af, bfv, acc[sub], 0, 0, 0);
        }
    }
    float asv[4], adv[4];
#pragma unroll
    for (int sub = 0; sub < 4; ++sub) {
        asv[sub] = a_src1[wave * 64 + sub * 16 + nl];
        adv[sub] = a_dst1[wave * 64 + sub * 16 + nl];
    }
#pragma unroll
    for (int r = 0; r < 4; ++r) {
        int gr = row0 + q * 4 + r;   // C/D: row = quad*4 + reg, col = lane&15
        float ps = 0.f, pd = 0.f;
#pragma unroll
        for (int sub = 0; sub < 4; ++sub) {
            float v = acc[sub][r];
            h1b[(size_t)gr * C1 + wave * 64 + sub * 16 + nl] = f2bf(v);
            ps += v * asv[sub];
            pd += v * adv[sub];
        }
#pragma unroll
        for (int m = 8; m >= 1; m >>= 1) {
            ps += __shfl_xor(ps, m, 16);
            pd += __shfl_xor(pd, m, 16);
        }
        if (nl == 0) {
            as1[gr * 4 + wave] = ps;
            ad1[gr * 4 + wave] = pd;
        }
    }
    // fused degree count: this block's 272-edge slice
    int base = blockIdx.x * EDGES_PER_G1;
    for (int e = base + t; e < base + EDGES_PER_G1; e += 256) {
        int s, d; edge_sd(ei, e, s, d);
        pos[e] = atomicAdd(&deg[d], 1);
    }
}

// ================================================================ scan: block-local scan + arrival-order chunk base
// row_start[n] = chunk_base + exclusive_prefix(deg within chunk). Disjoint, not monotonic.
__global__ __launch_bounds__(256) void scan_kernel(const int* __restrict__ deg,
                                                   int* __restrict__ counter,  // = &deg[50000], zeroed
                                                   int* __restrict__ row_start) {
    __shared__ int sm[256];
    __shared__ int base;
    int t = threadIdx.x, idx = blockIdx.x * 256 + t;
    int v = (idx < N_NODES) ? deg[idx] : 0;
    sm[t] = v; __syncthreads();
#pragma unroll
    for (int off = 1; off < 256; off <<= 1) {
        int u = (t >= off) ? sm[t - off] : 0;
        __syncthreads();
        sm[t] += u;
        __syncthreads();
    }
    if (t == 255) base = atomicAdd(counter, sm[255]);
    __syncthreads();
    if (idx < N_NODES) row_start[idx] = base + sm[t] - v;
}

// ================================================================ scatter: csr_src only (4 B/edge)
__global__ __launch_bounds__(256) void scatter_kernel(const int* __restrict__ ei,
                                                      const int* __restrict__ row_start,
                                                      const int* __restrict__ pos,
                                                      int* __restrict__ csr_src) {
    int e = blockIdx.x * 256 + threadIdx.x;
    if (e >= E_TOT) return;
    int s, d; edge_sd(ei, e, s, d);
    csr_src[row_start[d] + pos[e]] = s;
}

// ================================================================ agg1: 1 wave/dst, inline w, scalar addressing, unroll 16/8/8
__global__ __launch_bounds__(256) void agg1_kernel(const int* __restrict__ csr_src,
                                                   const int* __restrict__ row_start,
                                                   const int* __restrict__ deg,
                                                   const unsigned short* __restrict__ h1b,
                                                   const float* __restrict__ as1,
                                                   const float* __restrict__ ad1,
                                                   const float* __restrict__ b1,
                                                   unsigned short* __restrict__ hpb) {
    int n = (blockIdx.x * 256 + threadIdx.x) >> 6;
    if (n >= N_NODES) return;
    int lane = threadIdx.x & 63;
    int h = lane >> 4;
    int beg = __builtin_amdgcn_readfirstlane(row_start[n]);
    int end = beg + __builtin_amdgcn_readfirstlane(deg[n]);
    float ad = ad1[n * 4 + h];
    float4 acc = make_float4(0.f, 0.f, 0.f, 0.f);
    float sumw = 0.f;
    int i = beg;
    for (; i + 16 <= end; i += 16) {            // unmasked, 16-way MLP
        int s[16];
#pragma unroll
        for (int u = 0; u < 16; ++u) s[u] = __builtin_amdgcn_readfirstlane(csr_src[i + u]);
        float a[16];
#pragma unroll
        for (int u = 0; u < 16; ++u) a[u] = as1[s[u] * 4 + h];
        ushort4 rv[16];
#pragma unroll
        for (int u = 0; u < 16; ++u) rv[u] = *(const ushort4*)&h1b[(size_t)s[u] * C1 + lane * 4];
#pragma unroll
        for (int u = 0; u < 16; ++u) {
            float w = lrelu_exp(a[u] + ad);
            sumw += w;
            float4 f = bf4_to_f4(rv[u]);
            acc.x += w * f.x; acc.y += w * f.y;
            acc.z += w * f.z; acc.w += w * f.w;
        }
    }
    if (i + 8 <= end) {                          // unmasked, 8-way
        int s[8];
#pragma unroll
        for (int u = 0; u < 8; ++u) s[u] = __builtin_amdgcn_readfirstlane(csr_src[i + u]);
        float a[8];
#pragma unroll
        for (int u = 0; u < 8; ++u) a[u] = as1[s[u] * 4 + h];
        ushort4 rv[8];
#pragma unroll
        for (int u = 0; u < 8; ++u) rv[u] = *(const ushort4*)&h1b[(size_t)s[u] * C1 + lane * 4];
#pragma unroll
        for (int u = 0; u < 8; ++u) {
            float w = lrelu_exp(a[u] + ad);
            sumw += w;
            float4 f = bf4_to_f4(rv[u]);
            acc.x += w * f.x; acc.y += w * f.y;
            acc.z += w * f.z; acc.w += w * f.w;
        }
        i += 8;
    }
    if (i < end) {                               // masked tail, 8-way
        int s[8]; float va[8];
#pragma unroll
        for (int u = 0; u < 8; ++u) {
            bool v = (i + u) < end;
            va[u] = v ? 1.f : 0.f;
            s[u] = __builtin_amdgcn_readfirstlane(csr_src[v ? i + u : beg]);
        }
        float a[8];
#pragma unroll
        for (int u = 0; u < 8; ++u) a[u] = as1[s[u] * 4 + h];
        ushort4 rv[8];
#pragma unroll
        for (int u = 0; u < 8; ++u) rv[u] = *(const ushort4*)&h1b[(size_t)s[u] * C1 + lane * 4];
#pragma unroll
        for (int u = 0; u < 8; ++u) {
            float w = va[u] * lrelu_exp(a[u] + ad);
            sumw += w;
            float4 f = bf4_to_f4(rv[u]);
            acc.x += w * f.x; acc.y += w * f.y;
            acc.z += w * f.z; acc.w += w * f.w;
        }
    }
    float inv = 1.f / (sumw + 1e-16f);
    const float4 bv = *(const float4*)&b1[lane * 4];
    float v0 = acc.x * inv + bv.x;
    float v1 = acc.y * inv + bv.y;
    float v2 = acc.z * inv + bv.z;
    float v3 = acc.w * inv + bv.w;
    v0 = v0 > 0.f ? v0 : __expf(v0) - 1.f;
    v1 = v1 > 0.f ? v1 : __expf(v1) - 1.f;
    v2 = v2 > 0.f ? v2 : __expf(v2) - 1.f;
    v3 = v3 > 0.f ? v3 : __expf(v3) - 1.f;
    ushort4 o;
    o.x = f2bf(v0); o.y = f2bf(v1); o.z = f2bf(v2); o.w = f2bf(v3);
    *(ushort4*)&hpb[(size_t)n * C1 + lane * 4] = o;
}

// ================================================================ GEMM2 (MFMA bf16) + fused alpha2; h2 stored bf16
__global__ __launch_bounds__(256) void gemm2_kernel(const unsigned short* __restrict__ hpb,
                                                    const unsigned short* __restrict__ Bp2,
                                                    const float* __restrict__ a_src2,
                                                    const float* __restrict__ a_dst2,
                                                    unsigned short* __restrict__ h2b,
                                                    float* __restrict__ as2,
                                                    float* __restrict__ ad2) {
    __shared__ unsigned short xs[64][264];  // stride 264 shorts -> 2-way bank aliasing (free)
    const int t = threadIdx.x;
    const int row0 = blockIdx.x * 64;
    for (int idx = t; idx < 2048; idx += 256) {  // 64 rows x 32 chunks of 8
        int r = idx >> 5, ch = (idx & 31) * 8;
        int gr = row0 + r;
        u16x8 v = {0, 0, 0, 0, 0, 0, 0, 0};
        if (gr < N_NODES) v = *(const u16x8*)&hpb[(size_t)gr * C1 + ch];
        *(u16x8*)&xs[r][ch] = v;
    }
    __syncthreads();
    const int wave = t >> 6, lane = t & 63;
    const int nl = lane & 15, q = lane >> 4;
    f32x4 acc0 = {0.f, 0.f, 0.f, 0.f}, acc1 = {0.f, 0.f, 0.f, 0.f};
#pragma unroll
    for (int K0 = 0; K0 < 8; ++K0) {
        bf16x8 af = *(const bf16x8*)&xs[wave * 16 + nl][K0 * 32 + q * 8];
        bf16x8 b0 = *(const bf16x8*)&Bp2[((size_t)(K0 * 32 + nl) * 4 + q) * 8];
        bf16x8 b1v = *(const bf16x8*)&Bp2[((size_t)(K0 * 32 + 16 + nl) * 4 + q) * 8];
        acc0 = __builtin_amdgcn_mfma_f32_16x16x32_bf16(af, b0, acc0, 0, 0, 0);
        acc1 = __builtin_amdgcn_mfma_f32_16x16x32_bf16(af, b1v, acc1, 0, 0, 0);
    }
    float a_s0 = a_src2[nl], a_s1 = a_src2[16 + nl];
    float a_d0 = a_dst2[nl], a_d1 = a_dst2[16 + nl];
#pragma unroll
    for (int r = 0; r < 4; ++r) {
        int gr = row0 + wave * 16 + q * 4 + r;
        if (gr < N_NODES) {
            h2b[(size_t)gr * OUT_DIM + nl] = f2bf(acc0[r]);
            h2b[(size_t)gr * OUT_DIM + 16 + nl] = f2bf(acc1[r]);
            float ps = acc0[r] * a_s0 + acc1[r] * a_s1;
            float pd = acc0[r] * a_d0 + acc1[r] * a_d1;
#pragma unroll
            for (int m = 8; m >= 1; m >>= 1) {
                ps += __shfl_xor(ps, m, 16);
                pd += __shfl_xor(pd, m, 16);
            }
            if (nl == 0) { as2[gr] = ps; ad2[gr] = pd; }
        }
    }
}

// ================================================================ agg2: 1 wave/dst, 2x8 edges x 8 lanes x ushort4 (bf16 h2)
__global__ __launch_bounds__(256) void agg2_kernel(const int* __restrict__ csr_src,
                                                   const int* __restrict__ row_start,
                                                   const int* __restrict__ deg,
                                                   const unsigned short* __restrict__ h2b,
                                                   const float* __restrict__ as2,
                                                   const float* __restrict__ ad2,
                                                   const float* __restrict__ b2,
                                                   float* __restrict__ out) {
    int n = (blockIdx.x * 256 + threadIdx.x) >> 6;
    if (n >= N_NODES) return;
    int lane = threadIdx.x & 63;
    int g  = lane >> 3;          // edge slot 0..7
    int c4 = lane & 7;           // ushort4 chunk: cols [c4*4, c4*4+4)
    int beg = __builtin_amdgcn_readfirstlane(row_start[n]);
    int end = beg + __builtin_amdgcn_readfirstlane(deg[n]);
    float ad = ad2[n];
    float4 acc = make_float4(0.f, 0.f, 0.f, 0.f);
    float sumw = 0.f;
    for (int i = beg; i < end; i += 16) {        // two 8-edge batches in flight
#pragma unroll
        for (int b = 0; b < 2; ++b) {
            int idx = i + b * 8 + g;
            bool valid = idx < end;
            int ic = valid ? idx : beg;
            int s = csr_src[ic];
            float w = valid ? lrelu_exp(as2[s] + ad) : 0.f;
            sumw += w;
            float4 hv = bf4_to_f4(*(const ushort4*)&h2b[(size_t)s * OUT_DIM + c4 * 4]);
            acc.x += w * hv.x; acc.y += w * hv.y; acc.z += w * hv.z; acc.w += w * hv.w;
        }
    }
#pragma unroll
    for (int m = 8; m <= 32; m <<= 1) {
        sumw  += __shfl_xor(sumw, m, 64);
        acc.x += __shfl_xor(acc.x, m, 64);
        acc.y += __shfl_xor(acc.y, m, 64);
        acc.z += __shfl_xor(acc.z, m, 64);
        acc.w += __shfl_xor(acc.w, m, 64);
    }
    if (g == 0) {
        float inv = 1.f / (sumw + 1e-16f);
        const float4 bv = *(const float4*)&b2[c4 * 4];
        *(float4*)&out[(size_t)n * OUT_DIM + c4 * 4] =
            make_float4(acc.x * inv + bv.x, acc.y * inv + bv.y,
                        acc.z * inv + bv.z, acc.w * inv + bv.w);
    }
}

extern "C" void kernel_launch(void* const* d_in, const int* in_sizes, int n_in,
                              void* d_out, int out_size, void* d_ws, size_t ws_size,
                              hipStream_t stream) {
    const float* x      = (const float*)d_in[0];
    const int*   ei     = (const int*)d_in[1];
    const float* W1     = (const float*)d_in[2];
    const float* a_src1 = (const float*)d_in[3];
    const float* a_dst1 = (const float*)d_in[4];
    const float* b1     = (const float*)d_in[5];
    const float* W2     = (const float*)d_in[6];
    const float* a_src2 = (const float*)d_in[7];
    const float* a_dst2 = (const float*)d_in[8];
    const float* b2     = (const float*)d_in[9];
    float* out = (float*)d_out;

    // workspace layout
    unsigned short* h1b = (unsigned short*)d_ws;        // 12.8M bf16
    unsigned short* hpb = h1b + 12800000;               // 12.8M bf16
    unsigned short* h2b = hpb + 12800000;               // 1.6M bf16
    unsigned short* Bp1 = h2b + 1600000;                // 32768 bf16
    unsigned short* Bp2 = Bp1 + 32768;                  // 8192 bf16
    float* as1    = (float*)(Bp2 + 8192);               // 200k
    float* ad1    = as1 + 200000;                       // 200k
    float* as2    = ad1 + 200000;                       // 50k
    float* ad2    = as2 + 50000;                        // 50k
    int* csr_src  = (int*)(ad2 + 50000);                // 850k
    int* row_start= csr_src + E_TOT;                    // 50000
    int* deg      = row_start + N_NODES;                // 50001 (last = scan arrival counter)
    int* pos      = deg + N_NODES + 1;                  // 850k

    setup_kernel<<<SCAN_NBLK, 256, 0, stream>>>(W1, W2, Bp1, Bp2, deg);
    gemm1_kernel<<<G1_BLOCKS, 256, 0, stream>>>(x, Bp1, a_src1, a_dst1, ei,
                                                h1b, as1, ad1, deg, pos);
    scan_kernel<<<SCAN_NBLK, 256, 0, stream>>>(deg, deg + N_NODES, row_start);
    scatter_kernel<<<(E_TOT + 255) / 256, 256, 0, stream>>>(ei, row_start, pos, csr_src);
    agg1_kernel<<<(N_NODES * 64 + 255) / 256, 256, 0, stream>>>(csr_src, row_start, deg,
                                                                h1b, as1, ad1, b1, hpb);
    gemm2_kernel<<<(N_NODES + 63) / 64, 256, 0, stream>>>(hpb, Bp2, a_src2, a_dst2, h2b, as2, ad2);
    agg2_kernel<<<(N_NODES * 64 + 255) / 256, 256, 0, stream>>>(csr_src, row_start, deg,
                                                                h2b, as2, ad2, b2, out);
}